// Round 1
// baseline (277.409 us; speedup 1.0000x reference)
//
#include <hip/hip_runtime.h>
#include <cstdint>

// ---------------- problem constants ----------------
// features [8,2048,256] f32; Wq/Wk/Wv [256,512]; W2 [512,256]; b2 [256]
// out [8,2048,256] f32
#define NBATCH 8
#define NSEQ   2048
#define NROWS  16384  // 8*2048

typedef __attribute__((ext_vector_type(4))) float  f32x4;
typedef __attribute__((ext_vector_type(8))) short  short8;
typedef __attribute__((ext_vector_type(8))) __bf16 bf16x8;

// ---------------- workspace layout (bytes) ----------------
// all bf16 tensors stored row-XOR-swizzled: byte_in_row ^= ((row&7)<<4)
// (V^T uses ((row&3)<<4) since its staged windows are 64B)
#define XB_OFF   0ul          // Xb   [16384][256] bf16  = 8388608
#define WALL_OFF 8388608ul    // Wall [1536][256]  bf16  = 786432   (Wq^T*scale | Wk^T | Wv^T)
#define W2T_OFF  9175040ul    // W2t  [256][512]   bf16  = 262144
#define Q_OFF    9437184ul    // Q    [16384][512] bf16  = 16777216 (pre-scaled by 1/sqrt(512))
#define K_OFF    26214400ul   // K    [16384][512] bf16  = 16777216
#define VT_OFF   42991616ul   // Vt   [8][512][2048] bf16 = 16777216
// total = 59768832 bytes (~60 MB)

__device__ __forceinline__ unsigned short f2bf(float f) {
  unsigned u = __builtin_bit_cast(unsigned, f);
  return (unsigned short)((u + 0x7fffu + ((u >> 16) & 1u)) >> 16);  // RNE
}

__device__ __forceinline__ f32x4 mfma16(short8 a, short8 b, f32x4 c) {
  return __builtin_amdgcn_mfma_f32_16x16x32_bf16(
      __builtin_bit_cast(bf16x8, a), __builtin_bit_cast(bf16x8, b), c, 0, 0, 0);
}

__device__ __forceinline__ void glds16(const void* g, void* l) {
  __builtin_amdgcn_global_load_lds(
      (const __attribute__((address_space(1))) void*)g,
      (__attribute__((address_space(3))) void*)l, 16, 0, 0);
}

// ============================================================
// prep: bf16 conversions + transposes + swizzled layout
// 1,048,576 threads total
// ============================================================
__global__ __launch_bounds__(256, 4) void prep_kernel(
    const float* __restrict__ feat, const float* __restrict__ Wq,
    const float* __restrict__ Wk, const float* __restrict__ Wv,
    const float* __restrict__ W2, char* __restrict__ ws) {
  int tid = blockIdx.x * 256 + threadIdx.x;
  if (tid < 524288) {  // Xb: 8-elem chunks
    int r = tid >> 5, co = (tid & 31) * 8;
    const float* src = feat + (size_t)r * 256 + co;
    short8 v;
#pragma unroll
    for (int i = 0; i < 8; ++i) v[i] = (short)f2bf(src[i]);
    unsigned short* Xb = (unsigned short*)(ws + XB_OFF);
    *(short8*)(Xb + (size_t)r * 256 + (co ^ ((r & 7) << 3))) = v;
  } else if (tid < 917504) {  // Wall[m][d] = W*[d][m] (scale folded into Wq)
    int t2 = tid - 524288;
    int m = t2 >> 8, d = t2 & 255;
    int wsel = m >> 9, mm = m & 511;
    const float* W = (wsel == 0) ? Wq : ((wsel == 1) ? Wk : Wv);
    float v = W[(size_t)d * 512 + mm];
    if (wsel == 0) v *= 0.044194173824159216f;  // 1/sqrt(512)
    unsigned short* Wall = (unsigned short*)(ws + WALL_OFF);
    Wall[(size_t)m * 256 + (d ^ ((m & 7) << 3))] = f2bf(v);
  } else {  // W2t[d][c] = W2[c][d]
    int t3 = tid - 917504;
    int d = t3 >> 9, c = t3 & 511;
    unsigned short* W2t = (unsigned short*)(ws + W2T_OFF);
    W2t[(size_t)d * 512 + (c ^ ((d & 7) << 3))] = f2bf(W2[(size_t)c * 256 + d]);
  }
}

// ============================================================
// proj: [16384,256] @ [256, 512*3] -> Q, K (row-major), Vt (transposed)
// grid (12 ntiles, 128 mtiles), 4 waves, 128x128 tile, K=256 single stage
// ============================================================
__global__ __launch_bounds__(256, 2) void proj_kernel(char* __restrict__ ws) {
  __shared__ char smem[131072];  // A tile [128][512B] @0, B tile @65536
  const int tid = threadIdx.x;
  const int l = tid & 63, w = tid >> 6;
  const int g = l >> 4, m16 = l & 15;
  const int nt = blockIdx.x, mt = blockIdx.y;
  const char* XbT = ws + XB_OFF + (size_t)mt * 65536;
  const char* WallT = ws + WALL_OFF + (size_t)nt * 65536;
#pragma unroll
  for (int j = 0; j < 16; ++j) {
    int off = tid * 16 + j * 4096;
    glds16(XbT + off, smem + off);
    glds16(WallT + off, smem + 65536 + off);
  }
  __syncthreads();
  const int mr = (w >> 1) * 64, nr = (w & 1) * 64;
  const int fxor = (l & 7) << 4;
  const f32x4 fz = {0.f, 0.f, 0.f, 0.f};
  f32x4 acc[4][4];
#pragma unroll
  for (int i = 0; i < 4; ++i)
#pragma unroll
    for (int j = 0; j < 4; ++j) acc[i][j] = fz;
#pragma unroll
  for (int ks = 0; ks < 8; ++ks) {
    int cb = (16 * g + 64 * ks) ^ fxor;
    short8 af[4], bf[4];
#pragma unroll
    for (int i = 0; i < 4; ++i)
      af[i] = *(const short8*)(smem + (mr + i * 16 + m16) * 512 + cb);
#pragma unroll
    for (int i = 0; i < 4; ++i)
      bf[i] = *(const short8*)(smem + 65536 + (nr + i * 16 + m16) * 512 + cb);
#pragma unroll
    for (int mi = 0; mi < 4; ++mi)
#pragma unroll
      for (int ni = 0; ni < 4; ++ni)
        acc[mi][ni] = mfma16(af[mi], bf[ni], acc[mi][ni]);
  }
  __syncthreads();  // waves done reading A/B before repack reuses region
  const int tcat = (nt * 128 + nr) >> 9;       // 0=Q 1=K 2=V
  const int cin_base = (nt * 128 + nr) & 511;  // col within tensor
  char* wbuf = smem + w * 2048;                // per-wave [16][128B] repack buf
  const int grow_base = mt * 128 + mr;
#pragma unroll 1
  for (int mi = 0; mi < 4; ++mi) {
#pragma unroll
    for (int ni = 0; ni < 4; ++ni)
#pragma unroll
      for (int j = 0; j < 4; ++j) {
        int r = g * 4 + j, c = ni * 16 + m16;
        *(unsigned short*)(wbuf + r * 128 + ((2 * c) ^ ((r & 7) << 4))) =
            f2bf(acc[mi][ni][j]);
      }
    asm volatile("s_waitcnt lgkmcnt(0)" ::: "memory");
    __builtin_amdgcn_sched_barrier(0);
    if (tcat < 2) {  // Q / K: packed row-major stores
      char* dst = ws + (tcat == 0 ? Q_OFF : K_OFF);
#pragma unroll
      for (int s = 0; s < 2; ++s) {
        int cid = l + 64 * s;
        int r2 = cid >> 3, co = (cid & 7) * 8;
        short8 v = *(const short8*)(wbuf + r2 * 128 + ((2 * co) ^ ((r2 & 7) << 4)));
        int grow = grow_base + mi * 16 + r2;
        int cin = cin_base + co;
        *(short8*)(dst + (size_t)grow * 1024 + ((2 * cin) ^ ((grow & 7) << 4))) = v;
      }
    } else {  // V: transposed packed stores into Vt[b][cin][n]
      int cin = cin_base + l;
      int grow0 = grow_base + mi * 16;
      int bb = grow0 >> 11, n0 = grow0 & 2047;
      char* dstv = ws + VT_OFF + (size_t)bb * 2097152 + (size_t)cin * 4096;
      unsigned short vals[16];
#pragma unroll
      for (int r2 = 0; r2 < 16; ++r2)
        vals[r2] = *(const unsigned short*)(wbuf + r2 * 128 +
                                            ((2 * l) ^ ((r2 & 7) << 4)));
#pragma unroll
      for (int u = 0; u < 2; ++u) {
        short8 vv;
#pragma unroll
        for (int i2 = 0; i2 < 8; ++i2) vv[i2] = (short)vals[u * 8 + i2];
        *(short8*)(dstv + ((2 * n0 + 16 * u) ^ ((cin & 3) << 4))) = vv;
      }
    }
  }
}

// ============================================================
// attn: flash attention + fused fc2/bias/leakyrelu/residual
// grid (batch=8, qtile=32); 4 waves x 16 q-rows; KVBLK=32 double-buffered
// LDS: K bufs 2x32KB @0, Vt bufs 2x32KB @65536, P per-wave [16][72]bf16 @131072
// epilogue reuse: O-repack [4][16][1024B] @0, W2 chunk [64][1024B] @65536
// ============================================================
__global__ __launch_bounds__(256, 1) void attn_kernel(
    const char* __restrict__ ws, const float* __restrict__ feat,
    const float* __restrict__ b2, float* __restrict__ out) {
  __shared__ char smem[140288];
  const int tid = threadIdx.x;
  const int l = tid & 63, w = tid >> 6;
  const int g = l >> 4, m16 = l & 15;
  const int b = blockIdx.x, yq = blockIdx.y;

  const char* Qb = ws + Q_OFF;
  const char* Kb = ws + K_OFF + (size_t)b * 2097152;
  const char* Vb = ws + VT_OFF + (size_t)b * 2097152;
  const int fxor = (l & 7) << 4;

  // Q fragments: 16 k-steps, register resident (rows are this wave's 16 q-rows)
  const size_t qrow = (size_t)b * 2048 + yq * 64 + w * 16 + m16;
  short8 qf[16];
#pragma unroll
  for (int ks = 0; ks < 16; ++ks)
    qf[ks] = *(const short8*)(Qb + qrow * 1024 + ((16 * g + 64 * ks) ^ fxor));

  const f32x4 fz = {0.f, 0.f, 0.f, 0.f};
  f32x4 o[32];
#pragma unroll
  for (int i = 0; i < 32; ++i) o[i] = fz;
  float mrow[4] = {-1e30f, -1e30f, -1e30f, -1e30f};
  float lrow[4] = {0.f, 0.f, 0.f, 0.f};

  auto stage = [&](int buf, int kt2) {
    const char* kg = Kb + (size_t)kt2 * 32768;
    char* kl = smem + buf * 32768;
#pragma unroll
    for (int j = 0; j < 8; ++j) {
      int off = (w * 512 + j * 64 + l) * 16;
      glds16(kg + off, kl + off);
    }
    char* vl = smem + 65536 + buf * 32768;
#pragma unroll
    for (int j = 0; j < 8; ++j) {
      int chunk = w * 512 + j * 64 + l;
      int c = chunk >> 2, sub = chunk & 3;
      glds16(Vb + (size_t)c * 4096 + kt2 * 64 + sub * 16, vl + chunk * 16);
    }
  };

  stage(0, 0);
  __syncthreads();

  unsigned short* Pw = (unsigned short*)(smem + 131072 + w * 2304);
  const int kro = m16 * 1024;
  const int vxor = (l & 3) << 4;

#pragma unroll 2
  for (int kt = 0; kt < 64; ++kt) {
    const int cur = kt & 1;
    if (kt + 1 < 64) stage(cur ^ 1, kt + 1);  // overlap staging with compute
    // ---- S = Q @ K^T (pre-scaled), 16x32 per wave ----
    const char* kb = smem + cur * 32768;
    f32x4 s0 = fz, s1 = fz;
#pragma unroll
    for (int ks = 0; ks < 16; ++ks) {
      int cb = (16 * g + 64 * ks) ^ fxor;
      short8 k0 = *(const short8*)(kb + kro + cb);
      short8 k1 = *(const short8*)(kb + 16384 + kro + cb);
      s0 = mfma16(qf[ks], k0, s0);
      s1 = mfma16(qf[ks], k1, s1);
    }
    // ---- online softmax (rows live in 16-lane groups) ----
    float fac[4];
#pragma unroll
    for (int j = 0; j < 4; ++j) {
      float v = fmaxf(s0[j], s1[j]);
      v = fmaxf(v, __shfl_xor(v, 1));
      v = fmaxf(v, __shfl_xor(v, 2));
      v = fmaxf(v, __shfl_xor(v, 4));
      v = fmaxf(v, __shfl_xor(v, 8));
      float nm = fmaxf(mrow[j], v);
      fac[j] = __expf(mrow[j] - nm);
      mrow[j] = nm;
      float p0 = __expf(s0[j] - nm);
      float p1 = __expf(s1[j] - nm);
      float ps = p0 + p1;
      ps += __shfl_xor(ps, 1);
      ps += __shfl_xor(ps, 2);
      ps += __shfl_xor(ps, 4);
      ps += __shfl_xor(ps, 8);
      lrow[j] = lrow[j] * fac[j] + ps;
      int r = g * 4 + j;  // C-frag -> [16][72] LDS (A-frag transpose)
      Pw[r * 72 + m16] = f2bf(p0);
      Pw[r * 72 + 16 + m16] = f2bf(p1);
    }
    f32x4 fv = {fac[0], fac[1], fac[2], fac[3]};
#pragma unroll
    for (int ct = 0; ct < 32; ++ct) o[ct] *= fv;
    asm volatile("s_waitcnt lgkmcnt(0)" ::: "memory");
    __builtin_amdgcn_sched_barrier(0);
    // ---- O += P @ V (one P A-frag reused for all 32 c-tiles) ----
    short8 pa = *(const short8*)((const char*)Pw + m16 * 144 + 16 * g);
    const char* vb = smem + 65536 + cur * 32768;
#pragma unroll
    for (int ct = 0; ct < 32; ++ct) {
      short8 vf = *(const short8*)(vb + ct * 1024 + m16 * 64 + ((16 * g) ^ vxor));
      o[ct] = mfma16(pa, vf, o[ct]);
    }
    __syncthreads();  // drains next-tile staging; protects buffers
  }

  // ---- normalize + repack O (bf16) into LDS for fc2 A-frags ----
  float rl[4];
#pragma unroll
  for (int j = 0; j < 4; ++j) rl[j] = 1.0f / lrow[j];
  char* ob = smem + w * 16384;  // per-wave [16][1024B], XOR-swizzled
#pragma unroll
  for (int ct = 0; ct < 32; ++ct)
#pragma unroll
    for (int j = 0; j < 4; ++j) {
      int r = g * 4 + j, c = ct * 16 + m16;
      *(unsigned short*)(ob + r * 1024 + ((2 * c) ^ ((r & 7) << 4))) =
          f2bf(o[ct][j] * rl[j]);
    }
  // ---- fc2: Y = O @ W2 (+b2, leakyrelu, +residual) ----
  const char* W2b = ws + W2T_OFF;
  const size_t orow0 = (size_t)b * 2048 + yq * 64 + w * 16;
#pragma unroll 1
  for (int ch = 0; ch < 4; ++ch) {
    for (int j2 = 0; j2 < 16; ++j2) {  // stage W2t rows [ch*64,+64) -> 64KB
      int off = tid * 16 + j2 * 4096;
      glds16(W2b + ch * 65536 + off, smem + 65536 + off);
    }
    __syncthreads();
    f32x4 y[4] = {fz, fz, fz, fz};
#pragma unroll
    for (int ks = 0; ks < 16; ++ks) {
      int cb = (16 * g + 64 * ks) ^ fxor;
      short8 a = *(const short8*)(smem + w * 16384 + m16 * 1024 + cb);
#pragma unroll
      for (int ntt = 0; ntt < 4; ++ntt) {
        short8 wf = *(const short8*)(smem + 65536 + (ntt * 16 + m16) * 1024 + cb);
        y[ntt] = mfma16(a, wf, y[ntt]);
      }
    }
#pragma unroll
    for (int ntt = 0; ntt < 4; ++ntt) {
      int d = ch * 64 + ntt * 16 + m16;
      float bias = b2[d];
#pragma unroll
      for (int j = 0; j < 4; ++j) {
        size_t row = orow0 + g * 4 + j;
        float v = y[ntt][j] + bias;
        v = v > 0.f ? v : 0.2f * v;
        out[row * 256 + d] = v + feat[row * 256 + d];
      }
    }
    if (ch < 3) __syncthreads();
  }
}

// ============================================================
extern "C" void kernel_launch(void* const* d_in, const int* in_sizes, int n_in,
                              void* d_out, int out_size, void* d_ws, size_t ws_size,
                              hipStream_t stream) {
  const float* feat = (const float*)d_in[0];
  const float* Wq = (const float*)d_in[1];
  const float* Wk = (const float*)d_in[2];
  const float* Wv = (const float*)d_in[3];
  const float* W2 = (const float*)d_in[4];
  const float* b2 = (const float*)d_in[5];
  float* out = (float*)d_out;
  char* ws = (char*)d_ws;
  (void)in_sizes; (void)n_in; (void)out_size; (void)ws_size;

  prep_kernel<<<4096, 256, 0, stream>>>(feat, Wq, Wk, Wv, W2, ws);
  proj_kernel<<<dim3(12, 128), 256, 0, stream>>>(ws);
  attn_kernel<<<dim3(8, 32), 256, 0, stream>>>(ws, feat, b2, out);
}

// Round 2
// 258.023 us; speedup vs baseline: 1.0751x; 1.0751x over previous
//
#include <hip/hip_runtime.h>
#include <cstdint>

// ---------------- problem constants ----------------
// features [8,2048,256] f32; Wq/Wk/Wv [256,512]; W2 [512,256]; b2 [256]
// out [8,2048,256] f32
#define NBATCH 8
#define NSEQ   2048
#define NROWS  16384

typedef __attribute__((ext_vector_type(4))) float  f32x4;
typedef __attribute__((ext_vector_type(8))) short  short8;
typedef __attribute__((ext_vector_type(8))) __bf16 bf16x8;

// ---------------- workspace layout (bytes), total 59,768,832 ----------------
// Xb/Wall/W2t/Q/K: row-XOR-swizzled bf16 (byte_in_row ^= (row&7)<<4)
// Vt: LINEAR [b][c 512][n 2048] bf16 (slot swizzle applied at LDS-stage time)
#define XB_OFF   0ul          // Xb   [16384][256] bf16 = 8388608
#define WALL_OFF 8388608ul    // Wall [1536][256]  bf16 = 786432 (Wq^T*scale | Wk^T | Wv^T)
#define Q_OFF    9175040ul    // Q    [16384][512] bf16 = 16777216 (pre-scaled by log2e/sqrt(512))
#define K_OFF    25952256ul   // K    [16384][512] bf16 = 16777216
#define VT_OFF   42729472ul   // Vt   [8][512][2048] bf16 = 16777216
#define W2T_OFF  59506688ul   // W2t  [256][512]   bf16 = 262144

#define SCALE_Q 0.063758746f  // (1/sqrt(512)) * log2(e)

__device__ __forceinline__ unsigned short f2bf(float f) {
  unsigned u = __builtin_bit_cast(unsigned, f);
  return (unsigned short)((u + 0x7fffu + ((u >> 16) & 1u)) >> 16);  // RNE
}

__device__ __forceinline__ f32x4 mfma16(short8 a, short8 b, f32x4 c) {
  return __builtin_amdgcn_mfma_f32_16x16x32_bf16(
      __builtin_bit_cast(bf16x8, a), __builtin_bit_cast(bf16x8, b), c, 0, 0, 0);
}

__device__ __forceinline__ void glds16(const void* g, void* l) {
  __builtin_amdgcn_global_load_lds(
      (const __attribute__((address_space(1))) void*)g,
      (__attribute__((address_space(3))) void*)l, 16, 0, 0);
}

#define BAR_LGKM()                                           \
  {                                                          \
    asm volatile("s_waitcnt lgkmcnt(0)" ::: "memory");       \
    __builtin_amdgcn_sched_barrier(0);                       \
    __builtin_amdgcn_s_barrier();                            \
    __builtin_amdgcn_sched_barrier(0);                       \
  }
#define BAR_ALL()                                                    \
  {                                                                  \
    asm volatile("s_waitcnt vmcnt(0) lgkmcnt(0)" ::: "memory");      \
    __builtin_amdgcn_sched_barrier(0);                               \
    __builtin_amdgcn_s_barrier();                                    \
    __builtin_amdgcn_sched_barrier(0);                               \
  }

// ============================================================
// prep: bf16 conversions + transposes + swizzled layouts
// ============================================================
__global__ __launch_bounds__(256, 4) void prep_kernel(
    const float* __restrict__ feat, const float* __restrict__ Wq,
    const float* __restrict__ Wk, const float* __restrict__ Wv,
    const float* __restrict__ W2, char* __restrict__ ws) {
  int tid = blockIdx.x * 256 + threadIdx.x;
  if (tid < 524288) {  // Xb: 8-elem chunks
    int r = tid >> 5, co = (tid & 31) * 8;
    const float* src = feat + (size_t)r * 256 + co;
    short8 v;
#pragma unroll
    for (int i = 0; i < 8; ++i) v[i] = (short)f2bf(src[i]);
    unsigned short* Xb = (unsigned short*)(ws + XB_OFF);
    *(short8*)(Xb + (size_t)r * 256 + (co ^ ((r & 7) << 3))) = v;
  } else if (tid < 917504) {  // Wall[m][d] = W*[d][m] (scale folded into Wq)
    int t2 = tid - 524288;
    int m = t2 >> 8, d = t2 & 255;
    int wsel = m >> 9, mm = m & 511;
    const float* W = (wsel == 0) ? Wq : ((wsel == 1) ? Wk : Wv);
    float v = W[(size_t)d * 512 + mm];
    if (wsel == 0) v *= SCALE_Q;
    unsigned short* Wall = (unsigned short*)(ws + WALL_OFF);
    Wall[(size_t)m * 256 + (d ^ ((m & 7) << 3))] = f2bf(v);
  } else {  // W2t[d][c] = W2[c][d]
    int t3 = tid - 917504;
    int d = t3 >> 9, c = t3 & 511;
    unsigned short* W2t = (unsigned short*)(ws + W2T_OFF);
    W2t[(size_t)d * 512 + (c ^ ((d & 7) << 3))] = f2bf(W2[(size_t)c * 256 + d]);
  }
}

// ============================================================
// proj: [16384,256] @ [256, 512*3] -> Q, K (row-major swz), Vt (linear)
// grid (12 ntiles, 128 mtiles), 4 waves, 128x128 tile, K=256 single stage
// ============================================================
__global__ __launch_bounds__(256, 2) void proj_kernel(char* __restrict__ ws) {
  __shared__ char smem[131072];
  const int tid = threadIdx.x;
  const int l = tid & 63, w = tid >> 6;
  const int g = l >> 4, m16 = l & 15;
  const int nt = blockIdx.x, mt = blockIdx.y;
  const char* XbT = ws + XB_OFF + (size_t)mt * 65536;
  const char* WallT = ws + WALL_OFF + (size_t)nt * 65536;
#pragma unroll
  for (int j = 0; j < 16; ++j) {
    int off = tid * 16 + j * 4096;
    glds16(XbT + off, smem + off);
    glds16(WallT + off, smem + 65536 + off);
  }
  __syncthreads();
  const int mr = (w >> 1) * 64, nr = (w & 1) * 64;
  const int fxor = (l & 7) << 4;
  const f32x4 fz = {0.f, 0.f, 0.f, 0.f};
  f32x4 acc[4][4];
#pragma unroll
  for (int i = 0; i < 4; ++i)
#pragma unroll
    for (int j = 0; j < 4; ++j) acc[i][j] = fz;
#pragma unroll
  for (int ks = 0; ks < 8; ++ks) {
    int cb = (16 * g + 64 * ks) ^ fxor;
    short8 af[4], bf[4];
#pragma unroll
    for (int i = 0; i < 4; ++i)
      af[i] = *(const short8*)(smem + (mr + i * 16 + m16) * 512 + cb);
#pragma unroll
    for (int i = 0; i < 4; ++i)
      bf[i] = *(const short8*)(smem + 65536 + (nr + i * 16 + m16) * 512 + cb);
#pragma unroll
    for (int mi = 0; mi < 4; ++mi)
#pragma unroll
      for (int ni = 0; ni < 4; ++ni)
        acc[mi][ni] = mfma16(af[mi], bf[ni], acc[mi][ni]);
  }
  __syncthreads();
  const int tcat = (nt * 128 + nr) >> 9;       // 0=Q 1=K 2=V
  const int cin_base = (nt * 128 + nr) & 511;  // col within tensor
  char* wbuf = smem + w * 2048;                // per-wave [16][128B] repack buf
  const int grow_base = mt * 128 + mr;
#pragma unroll 1
  for (int mi = 0; mi < 4; ++mi) {
#pragma unroll
    for (int ni = 0; ni < 4; ++ni)
#pragma unroll
      for (int j = 0; j < 4; ++j) {
        int r = g * 4 + j, c = ni * 16 + m16;
        *(unsigned short*)(wbuf + r * 128 + ((2 * c) ^ ((r & 7) << 4))) =
            f2bf(acc[mi][ni][j]);
      }
    asm volatile("s_waitcnt lgkmcnt(0)" ::: "memory");
    __builtin_amdgcn_sched_barrier(0);
    if (tcat < 2) {  // Q / K: packed row-major swizzled stores
      char* dst = ws + (tcat == 0 ? Q_OFF : K_OFF);
#pragma unroll
      for (int s = 0; s < 2; ++s) {
        int cid = l + 64 * s;
        int r2 = cid >> 3, co = (cid & 7) * 8;
        short8 v = *(const short8*)(wbuf + r2 * 128 + ((2 * co) ^ ((r2 & 7) << 4)));
        int grow = grow_base + mi * 16 + r2;
        int cin = cin_base + co;
        *(short8*)(dst + (size_t)grow * 1024 + ((2 * cin) ^ ((grow & 7) << 4))) = v;
      }
    } else {  // V: transposed LINEAR stores into Vt[b][cin][n]
      int cin = cin_base + l;
      int grow0 = grow_base + mi * 16;
      int bb = grow0 >> 11, n0 = grow0 & 2047;
      char* dstv = ws + VT_OFF + (size_t)bb * 2097152 + (size_t)cin * 4096;
      unsigned short vals[16];
#pragma unroll
      for (int r2 = 0; r2 < 16; ++r2)
        vals[r2] = *(const unsigned short*)(wbuf + r2 * 128 +
                                            ((2 * l) ^ ((r2 & 7) << 4)));
#pragma unroll
      for (int u = 0; u < 2; ++u) {
        short8 vv;
#pragma unroll
        for (int i2 = 0; i2 < 8; ++i2) vv[i2] = (short)vals[u * 8 + i2];
        *(short8*)(dstv + 2 * n0 + 16 * u) = vv;
      }
    }
  }
}

// ============================================================
// attn: flash attention + fused fc2/bias/leakyrelu/residual
// grid (batch=8, qtile=32); 512 thr = 8 waves = 4 rowgroups x 2 halves
// wave (rg,h): 16 q-rows (rg), QK kv-half h, PV col-half h (256 cols)
// LDS: K 2x32KB @0, V 2x32KB @65536, P 4x1152B @131072, stats 512B @135680
// epilogue reuse: O [64][1024B] @0 (Kbufs), W2 chunks 2x32KB @65536 (Vbufs)
// ============================================================
__global__ __launch_bounds__(512, 2) void attn_kernel(
    const char* __restrict__ ws, const float* __restrict__ feat,
    const float* __restrict__ b2, float* __restrict__ out) {
  __shared__ char smem[136192];
  const int tid = threadIdx.x;
  const int l = tid & 63, w = tid >> 6;
  const int rg = w >> 1, h = w & 1;
  const int g = l >> 4, m16 = l & 15;
  const int b = blockIdx.x, yq = blockIdx.y;

  const char* Qb = ws + Q_OFF;
  const char* Kb = ws + K_OFF + (size_t)b * 2097152;
  const char* Vb = ws + VT_OFF + (size_t)b * 2097152;
  const int fxor = (m16 & 7) << 4;
  const int qrow0 = b * 2048 + yq * 64;

  // ---- Q fragments: 16 k-steps, register resident ----
  const char* qp = Qb + (size_t)(qrow0 + rg * 16 + m16) * 1024;
  const int qbe = (16 * g) ^ fxor, qbo = (16 * g + 64) ^ fxor;
  short8 qf[16];
#pragma unroll
  for (int ks = 0; ks < 16; ++ks)
    qf[ks] = *(const short8*)(qp + ((ks & 1) ? qbo : qbe) + 128 * (ks >> 1));

  const f32x4 fz = {0.f, 0.f, 0.f, 0.f};
  f32x4 o[16];
#pragma unroll
  for (int i = 0; i < 16; ++i) o[i] = fz;
  float mrow[4] = {-1e30f, -1e30f, -1e30f, -1e30f};
  float lrow[4] = {0.f, 0.f, 0.f, 0.f};

  auto stage = [&](int buf, int kt2) {
    const char* kg = Kb + (size_t)kt2 * 32768;
    char* kl = smem + buf * 32768;
#pragma unroll
    for (int j = 0; j < 4; ++j) {
      int idx = j * 512 + tid;
      glds16(kg + idx * 16, kl + idx * 16);
    }
    char* vl = smem + 65536 + buf * 32768;
#pragma unroll
    for (int j = 0; j < 4; ++j) {
      int idx = j * 512 + tid;
      int c = idx >> 2, ss = idx & 3;
      int st = ss ^ ((c >> 1) & 3);  // bank-swizzled slot placement
      glds16(Vb + (size_t)c * 4096 + kt2 * 64 + st * 16, vl + idx * 16);
    }
  };

  stage(0, 0);
  BAR_ALL();

  unsigned short* Pp = (unsigned short*)(smem + 131072 + rg * 1152);  // [16][36]
  float* statsF = (float*)(smem + 135680);                            // [2][4][16]
  const int krow = (16 * h + m16) * 1024;
  const int kbe = krow + ((16 * g) ^ fxor), kbo = krow + ((16 * g + 64) ^ fxor);
  const int vofs = m16 * 64 + ((16 * g) ^ (((m16 >> 1) & 3) << 4));
  const int paofs = m16 * 72 + g * 16;

#pragma unroll 2
  for (int kt = 0; kt < 64; ++kt) {
    const int cur = kt & 1;
    if (kt + 1 < 64) stage(cur ^ 1, kt + 1);
    // ---- S = Q @ K^T (pre-scaled by log2e/sqrt), 16x16 per wave ----
    const char* kb = smem + cur * 32768;
    f32x4 s = fz;
#pragma unroll
    for (int ks = 0; ks < 16; ++ks)
      s = mfma16(qf[ks],
                 *(const short8*)(kb + ((ks & 1) ? kbo : kbe) + 128 * (ks >> 1)),
                 s);
    // ---- online softmax: exchange row-max between halves ----
    float rmax[4];
#pragma unroll
    for (int j = 0; j < 4; ++j) {
      float v = s[j];
      v = fmaxf(v, __shfl_xor(v, 1));
      v = fmaxf(v, __shfl_xor(v, 2));
      v = fmaxf(v, __shfl_xor(v, 4));
      v = fmaxf(v, __shfl_xor(v, 8));
      rmax[j] = v;
      if (m16 == 0) statsF[h * 64 + rg * 16 + g * 4 + j] = v;
    }
    BAR_LGKM();  // B1: stats visible
    float mt[4];
#pragma unroll
    for (int j = 0; j < 4; ++j)
      mt[j] = fmaxf(rmax[j], statsF[(1 ^ h) * 64 + rg * 16 + g * 4 + j]);
    bool up = (mt[0] > mrow[0]) | (mt[1] > mrow[1]) | (mt[2] > mrow[2]) |
              (mt[3] > mrow[3]);
    if (__ballot(up)) {  // defer-max: skip rescale when max unchanged
      float fac[4];
#pragma unroll
      for (int j = 0; j < 4; ++j) {
        float mn = fmaxf(mrow[j], mt[j]);
        fac[j] = exp2f(mrow[j] - mn);
        mrow[j] = mn;
        lrow[j] *= fac[j];
      }
      f32x4 fv = {fac[0], fac[1], fac[2], fac[3]};
#pragma unroll
      for (int ct = 0; ct < 16; ++ct) o[ct] *= fv;
    }
#pragma unroll
    for (int j = 0; j < 4; ++j) {
      float p = exp2f(s[j] - mrow[j]);
      Pp[(g * 4 + j) * 36 + 16 * h + m16] = f2bf(p);
      float ps = p;
      ps += __shfl_xor(ps, 1);
      ps += __shfl_xor(ps, 2);
      ps += __shfl_xor(ps, 4);
      ps += __shfl_xor(ps, 8);
      lrow[j] += ps;  // partial over this wave's kv cols
    }
    BAR_LGKM();  // B2: P visible
    // ---- O += P @ V (16 col-tiles of this wave's 256-col half) ----
    short8 pa = *(const short8*)((const char*)Pp + paofs);
    const char* vb = smem + 65536 + cur * 32768 + h * 16384;
#pragma unroll
    for (int ct = 0; ct < 16; ++ct)
      o[ct] = mfma16(pa, *(const short8*)(vb + ct * 1024 + vofs), o[ct]);
    BAR_ALL();  // B3: staging drained + buffers free
  }

  // ---- merge partial l across halves; normalize ----
  if (m16 == 0) {
#pragma unroll
    for (int j = 0; j < 4; ++j) statsF[h * 64 + rg * 16 + g * 4 + j] = lrow[j];
  }
  BAR_LGKM();
  float rl[4];
#pragma unroll
  for (int j = 0; j < 4; ++j)
    rl[j] = 1.0f / (lrow[j] + statsF[(1 ^ h) * 64 + rg * 16 + g * 4 + j]);

  // ---- write O (bf16, row-swizzled) into LDS [64][1024B] over Kbufs ----
#pragma unroll
  for (int ct = 0; ct < 16; ++ct)
#pragma unroll
    for (int j = 0; j < 4; ++j) {
      int r = rg * 16 + g * 4 + j;
      *(unsigned short*)(smem + r * 1024 + h * 512 +
                         ((32 * ct + 2 * m16) ^ ((r & 7) << 4))) =
          f2bf(o[ct][j] * rl[j]);
    }
  BAR_LGKM();

  // ---- fc2: Y = O @ W2 (+bias, leakyrelu, +residual) ----
  // stage W2t in 8 chunks of 32 n-rows (32KB) into Vbuf halves, dbuf
  const char* W2b = ws + W2T_OFF;
  auto stageW2 = [&](int c, int buf) {
    char* dl = smem + 65536 + buf * 32768;
    const char* sg = W2b + (size_t)c * 32768;
#pragma unroll
    for (int j = 0; j < 4; ++j) {
      int idx = j * 512 + tid;
      glds16(sg + idx * 16, dl + idx * 16);
    }
  };
  stageW2(0, 0);
  // A-frags: this wave's 16 rows (rg), full k=512, from O-LDS
  const int arow = (rg * 16 + m16) * 1024;
  const int abe = arow + ((16 * g) ^ fxor), abo = arow + ((16 * g + 64) ^ fxor);
  short8 af[16];
#pragma unroll
  for (int ks = 0; ks < 16; ++ks)
    af[ks] = *(const short8*)(smem + ((ks & 1) ? abo : abe) + 128 * (ks >> 1));
  BAR_ALL();
#pragma unroll 1
  for (int c = 0; c < 8; ++c) {
    if (c < 8 - 1) stageW2(c + 1, (c + 1) & 1);
    const char* wb = smem + 65536 + (c & 1) * 32768;
    const int nrow = (h * 16 + m16) * 1024;
    const int wbe = nrow + ((16 * g) ^ fxor), wbo = nrow + ((16 * g + 64) ^ fxor);
    f32x4 y = fz;
#pragma unroll
    for (int ks = 0; ks < 16; ++ks)
      y = mfma16(af[ks],
                 *(const short8*)(wb + ((ks & 1) ? wbo : wbe) + 128 * (ks >> 1)),
                 y);
    int col = c * 32 + h * 16 + m16;
    float bias = b2[col];
#pragma unroll
    for (int j = 0; j < 4; ++j) {
      int gr = qrow0 + rg * 16 + g * 4 + j;
      float v = y[j] + bias;
      v = v > 0.f ? v : 0.2f * v;
      out[(size_t)gr * 256 + col] = v + feat[(size_t)gr * 256 + col];
    }
    BAR_ALL();
  }
}

// ============================================================
extern "C" void kernel_launch(void* const* d_in, const int* in_sizes, int n_in,
                              void* d_out, int out_size, void* d_ws, size_t ws_size,
                              hipStream_t stream) {
  const float* feat = (const float*)d_in[0];
  const float* Wq = (const float*)d_in[1];
  const float* Wk = (const float*)d_in[2];
  const float* Wv = (const float*)d_in[3];
  const float* W2 = (const float*)d_in[4];
  const float* b2 = (const float*)d_in[5];
  float* out = (float*)d_out;
  char* ws = (char*)d_ws;
  (void)in_sizes; (void)n_in; (void)out_size; (void)ws_size;

  prep_kernel<<<4096, 256, 0, stream>>>(feat, Wq, Wk, Wv, W2, ws);
  proj_kernel<<<dim3(12, 128), 256, 0, stream>>>(ws);
  attn_kernel<<<dim3(8, 32), 512, 0, stream>>>(ws, feat, b2, out);
}